// Round 1
// baseline (704.345 us; speedup 1.0000x reference)
//
#include <hip/hip_runtime.h>
#include <hip/hip_bf16.h>
#include <math.h>

#define B 64
#define CIN 96
#define HH 28
#define WW 28
#define NPIX 784
#define E 4
#define HID 576
#define RED 24
#define RHID 24
#define COUT 96
#define EPS 1e-3f

__device__ __forceinline__ float sigmoidf_(float v) { return 1.0f / (1.0f + __expf(-v)); }

// ---------------- K1: routing: pool -> MLP -> softmax -> rw[B,E] ----------------
__global__ void k_routing(const float* __restrict__ x,
                          const float* __restrict__ r_w1, const float* __restrict__ r_b1,
                          const float* __restrict__ r_w2, const float* __restrict__ r_b2,
                          float* __restrict__ rw) {
    int b = blockIdx.x;
    int tid = threadIdx.x;
    int wave = tid >> 6, lane = tid & 63;
    __shared__ float pool[CIN];
    __shared__ float hdn[RHID];
    const float* xb = x + (size_t)b * CIN * NPIX;
    for (int c = wave; c < CIN; c += 4) {
        float s = 0.f;
        for (int p = lane; p < NPIX; p += 64) s += xb[c * NPIX + p];
#pragma unroll
        for (int off = 32; off > 0; off >>= 1) s += __shfl_down(s, off);
        if (lane == 0) pool[c] = s * (1.0f / NPIX);
    }
    __syncthreads();
    if (tid < RHID) {
        float a = r_b1[tid];
        for (int c = 0; c < CIN; ++c) a += pool[c] * r_w1[tid * CIN + c];
        hdn[tid] = fmaxf(a, 0.f);
    }
    __syncthreads();
    if (tid == 0) {
        float lg[E];
        float mx = -1e30f;
#pragma unroll
        for (int e = 0; e < E; ++e) {
            float a = r_b2[e];
            for (int r = 0; r < RHID; ++r) a += hdn[r] * r_w2[e * RHID + r];
            lg[e] = a;
            mx = fmaxf(mx, a);
        }
        float den = 0.f;
#pragma unroll
        for (int e = 0; e < E; ++e) { lg[e] = __expf(lg[e] - mx); den += lg[e]; }
#pragma unroll
        for (int e = 0; e < E; ++e) rw[b * E + e] = lg[e] / den;
    }
}

// ---------------- K2: kern[b,c,25] = inv2[c] * sum_e rw[b,e]*dw_w[e,c,25] ----------------
__global__ void k_kern_agg(const float* __restrict__ rw, const float* __restrict__ dw_w,
                           const float* __restrict__ bn2_g, const float* __restrict__ bn2_v,
                           float* __restrict__ kern) {
    const int per = HID * 25;  // 14400
    int idx = blockIdx.x * blockDim.x + threadIdx.x;
    if (idx >= B * per) return;
    int b = idx / per, j = idx % per;
    int c = j / 25;
    const float* rwb = rw + b * E;
    float a = 0.f;
#pragma unroll
    for (int e = 0; e < E; ++e) a += rwb[e] * dw_w[(size_t)e * per + j];
    float inv2 = bn2_g[c] * rsqrtf(bn2_v[c] + EPS);
    kern[idx] = a * inv2;
}

// ---------------- K3: expand GEMM + BN1 + SiLU -> hid (bf16) ----------------
__global__ __launch_bounds__(256, 2) void k_expand(
    const float* __restrict__ x, const float* __restrict__ exp_w,
    const float* __restrict__ bn1_g, const float* __restrict__ bn1_b,
    const float* __restrict__ bn1_m, const float* __restrict__ bn1_v,
    __hip_bfloat16* __restrict__ hid) {
    const int OCT = 16;
    int ot = blockIdx.x;  // 0..35
    int b = blockIdx.y;
    int tid = threadIdx.x;
    int ocb = ot * OCT;
    __shared__ float Wl[OCT * CIN];
    for (int i = tid; i < OCT * CIN; i += 256) Wl[i] = exp_w[(size_t)ocb * CIN + i];
    __syncthreads();
    const float* xb = x + (size_t)b * CIN * NPIX;
    float acc[4][OCT] = {};
    bool a3 = (tid + 768) < NPIX;
#pragma unroll 4
    for (int c = 0; c < CIN; ++c) {
        const float* xc = xb + c * NPIX;
        float x0 = xc[tid];
        float x1 = xc[tid + 256];
        float x2 = xc[tid + 512];
        float x3 = a3 ? xc[tid + 768] : 0.f;
#pragma unroll
        for (int o = 0; o < OCT; ++o) {
            float w = Wl[o * CIN + c];
            acc[0][o] += w * x0;
            acc[1][o] += w * x1;
            acc[2][o] += w * x2;
            acc[3][o] += w * x3;
        }
    }
#pragma unroll
    for (int o = 0; o < OCT; ++o) {
        int oc = ocb + o;
        float inv1 = bn1_g[oc] * rsqrtf(bn1_v[oc] + EPS);
        float sh1 = bn1_b[oc] - bn1_m[oc] * inv1;
        __hip_bfloat16* hp = hid + ((size_t)b * HID + oc) * NPIX;
#pragma unroll
        for (int s = 0; s < 4; ++s) {
            int p = s * 256 + tid;
            if (p < NPIX) {
                float t = acc[s][o] * inv1 + sh1;
                float u = t * sigmoidf_(t);
                hp[p] = __float2bfloat16(u);
            }
        }
    }
}

// ---------------- K4: per-sample depthwise 5x5 + BN2 + SiLU (in-place) + channel means ----------------
__global__ __launch_bounds__(256, 2) void k_dw(
    __hip_bfloat16* __restrict__ hid, const float* __restrict__ kern,
    const float* __restrict__ bn2_g, const float* __restrict__ bn2_b,
    const float* __restrict__ bn2_m, const float* __restrict__ bn2_v,
    float* __restrict__ s_out) {
    const int CT = 16;
    int ct = blockIdx.x;  // 0..35
    int b = blockIdx.y;
    int tid = threadIdx.x;
    int cb = ct * CT;
    __shared__ float plane[CT][NPIX];  // 50 KB
    __shared__ float kl[CT][25];
    __shared__ float ssum[CT];
    __hip_bfloat16* hb = hid + ((size_t)b * HID + cb) * NPIX;
    for (int i = tid; i < CT * NPIX; i += 256) plane[i / NPIX][i % NPIX] = __bfloat162float(hb[i]);
    for (int i = tid; i < CT * 25; i += 256) kl[i / 25][i % 25] = kern[((size_t)b * HID + cb) * 25 + i];
    if (tid < CT) ssum[tid] = 0.f;
    __syncthreads();
    for (int pass = 0; pass < 2; ++pass) {
        int col = pass * 256 + tid;
        if (col < CT * WW) {
            int ci = col / WW, w = col % WW;
            float k[25];
#pragma unroll
            for (int j = 0; j < 25; ++j) k[j] = kl[ci][j];
            float win[5][5];
#pragma unroll
            for (int i = 0; i < 5; ++i) {
                int hr = i - 2;
#pragma unroll
                for (int j = 0; j < 5; ++j) {
                    int wc = w - 2 + j;
                    win[i][j] = (hr >= 0 && hr < HH && wc >= 0 && wc < WW) ? plane[ci][hr * WW + wc] : 0.f;
                }
            }
            int c = cb + ci;
            float inv2 = bn2_g[c] * rsqrtf(bn2_v[c] + EPS);
            float sh2 = bn2_b[c] - bn2_m[c] * inv2;
            float csum = 0.f;
#pragma unroll
            for (int h = 0; h < HH; ++h) {
                float o = 0.f;
#pragma unroll
                for (int i = 0; i < 5; ++i)
#pragma unroll
                    for (int j = 0; j < 5; ++j) o += win[i][j] * k[i * 5 + j];
                float t = o + sh2;  // conv already scaled by inv2 (folded into kern)
                float u = t * sigmoidf_(t);
                csum += u;
                hb[ci * NPIX + h * WW + w] = __float2bfloat16(u);
#pragma unroll
                for (int i = 0; i < 4; ++i)
#pragma unroll
                    for (int j = 0; j < 5; ++j) win[i][j] = win[i + 1][j];
                int hn = h + 3;
#pragma unroll
                for (int j = 0; j < 5; ++j) {
                    int wc = w - 2 + j;
                    win[4][j] = (hn < HH && wc >= 0 && wc < WW) ? plane[ci][hn * WW + wc] : 0.f;
                }
            }
            atomicAdd(&ssum[ci], csum);
        }
    }
    __syncthreads();
    if (tid < CT) s_out[(size_t)b * HID + cb + tid] = ssum[tid] * (1.0f / NPIX);
}

// ---------------- K5: SE MLP -> sc; wpw[b,o,c] = inv3[o]*sc[c]*sum_e rw*pw_w ----------------
__global__ void k_se_wpw(const float* __restrict__ s, const float* __restrict__ se_w1,
                         const float* __restrict__ se_b1, const float* __restrict__ se_w2,
                         const float* __restrict__ se_b2, const float* __restrict__ rw,
                         const float* __restrict__ pw_w,
                         const float* __restrict__ bn3_g, const float* __restrict__ bn3_v,
                         float* __restrict__ wpw) {
    int b = blockIdx.x;
    int tid = threadIdx.x;
    __shared__ float sl[HID];
    __shared__ float zl[RED];
    __shared__ float scl[HID];
    for (int i = tid; i < HID; i += 256) sl[i] = s[(size_t)b * HID + i];
    __syncthreads();
    if (tid < RED) {
        float a = se_b1[tid];
        for (int c = 0; c < HID; ++c) a += sl[c] * se_w1[tid * HID + c];
        zl[tid] = a * sigmoidf_(a);
    }
    __syncthreads();
    for (int c = tid; c < HID; c += 256) {
        float a = se_b2[c];
#pragma unroll
        for (int r = 0; r < RED; ++r) a += zl[r] * se_w2[c * RED + r];
        scl[c] = sigmoidf_(a);
    }
    __syncthreads();
    float rwl[E];
#pragma unroll
    for (int e = 0; e < E; ++e) rwl[e] = rw[b * E + e];
    float* wb = wpw + (size_t)b * COUT * HID;
    for (int i = tid; i < COUT * HID; i += 256) {
        int o = i / HID, c = i % HID;
        float a = 0.f;
#pragma unroll
        for (int e = 0; e < E; ++e) a += rwl[e] * pw_w[(size_t)e * COUT * HID + i];
        float inv3 = bn3_g[o] * rsqrtf(bn3_v[o] + EPS);
        wb[i] = a * inv3 * scl[c];
    }
}

// ---------------- K6: pointwise GEMM + BN3 shift + residual -> out ----------------
__global__ __launch_bounds__(256, 2) void k_pw(
    const __hip_bfloat16* __restrict__ hid, const float* __restrict__ wpw,
    const float* __restrict__ x,
    const float* __restrict__ bn3_g, const float* __restrict__ bn3_b,
    const float* __restrict__ bn3_m, const float* __restrict__ bn3_v,
    float* __restrict__ out) {
    const int OCT = 8;
    int ot = blockIdx.x;  // 0..11
    int b = blockIdx.y;
    int tid = threadIdx.x;
    int ocb = ot * OCT;
    __shared__ float Wl[OCT * HID];  // 18 KB
    const float* wb = wpw + ((size_t)b * COUT + ocb) * HID;
    for (int i = tid; i < OCT * HID; i += 256) Wl[i] = wb[i];
    __syncthreads();
    const __hip_bfloat16* hbase = hid + (size_t)b * HID * NPIX;
    float acc[4][OCT] = {};
    bool a3 = (tid + 768) < NPIX;
#pragma unroll 4
    for (int c = 0; c < HID; ++c) {
        const __hip_bfloat16* hc = hbase + c * NPIX;
        float x0 = __bfloat162float(hc[tid]);
        float x1 = __bfloat162float(hc[tid + 256]);
        float x2 = __bfloat162float(hc[tid + 512]);
        float x3 = a3 ? __bfloat162float(hc[tid + 768]) : 0.f;
#pragma unroll
        for (int o = 0; o < OCT; ++o) {
            float w = Wl[o * HID + c];
            acc[0][o] += w * x0;
            acc[1][o] += w * x1;
            acc[2][o] += w * x2;
            acc[3][o] += w * x3;
        }
    }
#pragma unroll
    for (int o = 0; o < OCT; ++o) {
        int oc = ocb + o;
        float inv3 = bn3_g[oc] * rsqrtf(bn3_v[oc] + EPS);
        float sh3 = bn3_b[oc] - bn3_m[oc] * inv3;
        const float* xr = x + ((size_t)b * COUT + oc) * NPIX;
        float* orow = out + ((size_t)b * COUT + oc) * NPIX;
#pragma unroll
        for (int s = 0; s < 4; ++s) {
            int p = s * 256 + tid;
            if (p < NPIX) orow[p] = acc[s][o] + sh3 + xr[p];
        }
    }
}

extern "C" void kernel_launch(void* const* d_in, const int* in_sizes, int n_in,
                              void* d_out, int out_size, void* d_ws, size_t ws_size,
                              hipStream_t stream) {
    const float* x     = (const float*)d_in[0];
    const float* r_w1  = (const float*)d_in[1];
    const float* r_b1  = (const float*)d_in[2];
    const float* r_w2  = (const float*)d_in[3];
    const float* r_b2  = (const float*)d_in[4];
    const float* exp_w = (const float*)d_in[5];
    const float* bn1_g = (const float*)d_in[6];
    const float* bn1_b = (const float*)d_in[7];
    const float* bn1_m = (const float*)d_in[8];
    const float* bn1_v = (const float*)d_in[9];
    const float* dw_w  = (const float*)d_in[10];
    const float* bn2_g = (const float*)d_in[11];
    const float* bn2_b = (const float*)d_in[12];
    const float* bn2_m = (const float*)d_in[13];
    const float* bn2_v = (const float*)d_in[14];
    const float* se_w1 = (const float*)d_in[15];
    const float* se_b1 = (const float*)d_in[16];
    const float* se_w2 = (const float*)d_in[17];
    const float* se_b2 = (const float*)d_in[18];
    const float* pw_w  = (const float*)d_in[19];
    const float* bn3_g = (const float*)d_in[20];
    const float* bn3_b = (const float*)d_in[21];
    const float* bn3_m = (const float*)d_in[22];
    const float* bn3_v = (const float*)d_in[23];
    float* out = (float*)d_out;

    char* ws = (char*)d_ws;
    // offsets (256-aligned)
    float* rw            = (float*)(ws + 0);          // 64*4*4      = 1 KB
    float* kern          = (float*)(ws + 1024);       // 64*576*25*4 = 3.69 MB
    float* s             = (float*)(ws + 3687424);    // 64*576*4
    float* wpw           = (float*)(ws + 3834880);    // 64*96*576*4 = 14.2 MB
    __hip_bfloat16* hid  = (__hip_bfloat16*)(ws + 17990656);  // 64*576*784*2 = 57.8 MB

    k_routing<<<B, 256, 0, stream>>>(x, r_w1, r_b1, r_w2, r_b2, rw);
    k_kern_agg<<<(B * HID * 25 + 255) / 256, 256, 0, stream>>>(rw, dw_w, bn2_g, bn2_v, kern);
    k_expand<<<dim3(36, B), 256, 0, stream>>>(x, exp_w, bn1_g, bn1_b, bn1_m, bn1_v, hid);
    k_dw<<<dim3(36, B), 256, 0, stream>>>(hid, kern, bn2_g, bn2_b, bn2_m, bn2_v, s);
    k_se_wpw<<<B, 256, 0, stream>>>(s, se_w1, se_b1, se_w2, se_b2, rw, pw_w, bn3_g, bn3_v, wpw);
    k_pw<<<dim3(12, B), 256, 0, stream>>>(hid, wpw, x, bn3_g, bn3_b, bn3_m, bn3_v, out);
}

// Round 2
// 460.545 us; speedup vs baseline: 1.5294x; 1.5294x over previous
//
#include <hip/hip_runtime.h>
#include <hip/hip_bf16.h>
#include <math.h>

#define B 64
#define CIN 96
#define HH 28
#define WW 28
#define NPIX 784
#define E 4
#define HID 576
#define RED 24
#define RHID 24
#define COUT 96
#define EPS 1e-3f

typedef __attribute__((ext_vector_type(8))) short short8v;
typedef __attribute__((ext_vector_type(4))) float f32x4;

__device__ __forceinline__ float sigmoidf_(float v) { return 1.0f / (1.0f + __expf(-v)); }

__device__ __forceinline__ unsigned short f2bf(float v) {
    __hip_bfloat16 h = __float2bfloat16(v);
    return *reinterpret_cast<unsigned short*>(&h);
}

// ---------------- K1: routing: pool -> MLP -> softmax -> rw[B,E] ----------------
__global__ void k_routing(const float* __restrict__ x,
                          const float* __restrict__ r_w1, const float* __restrict__ r_b1,
                          const float* __restrict__ r_w2, const float* __restrict__ r_b2,
                          float* __restrict__ rw) {
    int b = blockIdx.x;
    int tid = threadIdx.x;
    int wave = tid >> 6, lane = tid & 63;
    __shared__ float pool[CIN];
    __shared__ float hdn[RHID];
    const float* xb = x + (size_t)b * CIN * NPIX;
    for (int c = wave; c < CIN; c += 4) {
        float s = 0.f;
        for (int p = lane; p < NPIX; p += 64) s += xb[c * NPIX + p];
#pragma unroll
        for (int off = 32; off > 0; off >>= 1) s += __shfl_down(s, off);
        if (lane == 0) pool[c] = s * (1.0f / NPIX);
    }
    __syncthreads();
    if (tid < RHID) {
        float a = r_b1[tid];
        for (int c = 0; c < CIN; ++c) a += pool[c] * r_w1[tid * CIN + c];
        hdn[tid] = fmaxf(a, 0.f);
    }
    __syncthreads();
    if (tid == 0) {
        float lg[E];
        float mx = -1e30f;
#pragma unroll
        for (int e = 0; e < E; ++e) {
            float a = r_b2[e];
            for (int r = 0; r < RHID; ++r) a += hdn[r] * r_w2[e * RHID + r];
            lg[e] = a;
            mx = fmaxf(mx, a);
        }
        float den = 0.f;
#pragma unroll
        for (int e = 0; e < E; ++e) { lg[e] = __expf(lg[e] - mx); den += lg[e]; }
#pragma unroll
        for (int e = 0; e < E; ++e) rw[b * E + e] = lg[e] / den;
    }
}

// ---------------- K2: kern[b,c,25] = inv2[c] * sum_e rw[b,e]*dw_w[e,c,25] ----------------
__global__ void k_kern_agg(const float* __restrict__ rw, const float* __restrict__ dw_w,
                           const float* __restrict__ bn2_g, const float* __restrict__ bn2_v,
                           float* __restrict__ kern) {
    const int per = HID * 25;  // 14400
    int idx = blockIdx.x * blockDim.x + threadIdx.x;
    if (idx >= B * per) return;
    int b = idx / per, j = idx % per;
    int c = j / 25;
    const float* rwb = rw + b * E;
    float a = 0.f;
#pragma unroll
    for (int e = 0; e < E; ++e) a += rwb[e] * dw_w[(size_t)e * per + j];
    float inv2 = bn2_g[c] * rsqrtf(bn2_v[c] + EPS);
    kern[idx] = a * inv2;
}

// ---------------- K2b: exp_w -> bf16 ----------------
__global__ void k_wcvt(const float* __restrict__ w, unsigned short* __restrict__ wb) {
    int i = blockIdx.x * blockDim.x + threadIdx.x;
    if (i < HID * CIN) wb[i] = f2bf(w[i]);
}

// ---------------- K3: expand GEMM (MFMA bf16) + BN1 + SiLU -> hid (bf16 [b][c][p]) ----------------
// block = (n-chunk of 112 px, b); 4 waves; wave w owns m-frags w*9..w*9+8 (144 rows)
__global__ __launch_bounds__(256) void k_expand_mfma(
    const float* __restrict__ x, const unsigned short* __restrict__ w_bf,  // [576][96] bf16
    const float* __restrict__ bn1_g, const float* __restrict__ bn1_b,
    const float* __restrict__ bn1_m, const float* __restrict__ bn1_v,
    __hip_bfloat16* __restrict__ hid) {
    int nc = blockIdx.x;  // 0..6
    int b = blockIdx.y;
    int tid = threadIdx.x;
    int lane = tid & 63, wv = tid >> 6;
    int col = lane & 15, g = lane >> 4;
    __shared__ unsigned short xt[96 * 116];  // [k=96][px=112 pad 116] bf16
    __shared__ float inv1s[HID], sh1s[HID];

    // fold BN1
    for (int i = tid; i < HID; i += 256) {
        float inv = bn1_g[i] * rsqrtf(bn1_v[i] + EPS);
        inv1s[i] = inv;
        sh1s[i] = bn1_b[i] - bn1_m[i] * inv;
    }
    // stage x tile (fp32 -> bf16)
    const float* xb = x + (size_t)b * CIN * NPIX + nc * 112;
    for (int i = tid; i < 96 * 112; i += 256) {
        int c = i / 112, p = i % 112;
        xt[c * 116 + p] = f2bf(xb[c * NPIX + p]);
    }
    __syncthreads();

    const short8v* wv8 = reinterpret_cast<const short8v*>(w_bf);
    for (int nf = 0; nf < 7; ++nf) {
        int pcol = nf * 16 + col;
        short8v bfr[3];
#pragma unroll
        for (int kk = 0; kk < 3; ++kk) {
            int k0 = kk * 32 + 8 * g;
#pragma unroll
            for (int j = 0; j < 8; ++j) bfr[kk][j] = (short)xt[(k0 + j) * 116 + pcol];
        }
        int px = nc * 112 + pcol;
#pragma unroll
        for (int mi = 0; mi < 9; ++mi) {
            int mb = (wv * 9 + mi) * 16;
            f32x4 acc = {0.f, 0.f, 0.f, 0.f};
#pragma unroll
            for (int kk = 0; kk < 3; ++kk) {
                short8v af = wv8[((mb + col) * 96 + kk * 32 + 8 * g) >> 3];
                acc = __builtin_amdgcn_mfma_f32_16x16x32_bf16(af, bfr[kk], acc, 0, 0, 0);
            }
#pragma unroll
            for (int r = 0; r < 4; ++r) {
                int oc = mb + 4 * g + r;
                float t = acc[r] * inv1s[oc] + sh1s[oc];
                float u = t * sigmoidf_(t);
                hid[((size_t)b * HID + oc) * NPIX + px] = __float2bfloat16(u);
            }
        }
    }
}

// ---------------- K4: per-sample depthwise 5x5 + BN2 + SiLU (in-place) + channel means ----------------
__global__ __launch_bounds__(256, 2) void k_dw(
    __hip_bfloat16* __restrict__ hid, const float* __restrict__ kern,
    const float* __restrict__ bn2_g, const float* __restrict__ bn2_b,
    const float* __restrict__ bn2_m, const float* __restrict__ bn2_v,
    float* __restrict__ s_out) {
    const int CT = 16;
    int ct = blockIdx.x;  // 0..35
    int b = blockIdx.y;
    int tid = threadIdx.x;
    int cb = ct * CT;
    __shared__ float plane[CT][NPIX];  // 50 KB
    __shared__ float kl[CT][25];
    __shared__ float ssum[CT];
    __hip_bfloat16* hb = hid + ((size_t)b * HID + cb) * NPIX;
    for (int i = tid; i < CT * NPIX; i += 256) plane[i / NPIX][i % NPIX] = __bfloat162float(hb[i]);
    for (int i = tid; i < CT * 25; i += 256) kl[i / 25][i % 25] = kern[((size_t)b * HID + cb) * 25 + i];
    if (tid < CT) ssum[tid] = 0.f;
    __syncthreads();
    for (int pass = 0; pass < 2; ++pass) {
        int col = pass * 256 + tid;
        if (col < CT * WW) {
            int ci = col / WW, w = col % WW;
            float k[25];
#pragma unroll
            for (int j = 0; j < 25; ++j) k[j] = kl[ci][j];
            float win[5][5];
#pragma unroll
            for (int i = 0; i < 5; ++i) {
                int hr = i - 2;
#pragma unroll
                for (int j = 0; j < 5; ++j) {
                    int wc = w - 2 + j;
                    win[i][j] = (hr >= 0 && hr < HH && wc >= 0 && wc < WW) ? plane[ci][hr * WW + wc] : 0.f;
                }
            }
            int c = cb + ci;
            float inv2 = bn2_g[c] * rsqrtf(bn2_v[c] + EPS);
            float sh2 = bn2_b[c] - bn2_m[c] * inv2;
            float csum = 0.f;
#pragma unroll
            for (int h = 0; h < HH; ++h) {
                float o = 0.f;
#pragma unroll
                for (int i = 0; i < 5; ++i)
#pragma unroll
                    for (int j = 0; j < 5; ++j) o += win[i][j] * k[i * 5 + j];
                float t = o + sh2;  // conv already scaled by inv2 (folded into kern)
                float u = t * sigmoidf_(t);
                csum += u;
                hb[ci * NPIX + h * WW + w] = __float2bfloat16(u);
#pragma unroll
                for (int i = 0; i < 4; ++i)
#pragma unroll
                    for (int j = 0; j < 5; ++j) win[i][j] = win[i + 1][j];
                int hn = h + 3;
#pragma unroll
                for (int j = 0; j < 5; ++j) {
                    int wc = w - 2 + j;
                    win[4][j] = (hn < HH && wc >= 0 && wc < WW) ? plane[ci][hn * WW + wc] : 0.f;
                }
            }
            atomicAdd(&ssum[ci], csum);
        }
    }
    __syncthreads();
    if (tid < CT) s_out[(size_t)b * HID + cb + tid] = ssum[tid] * (1.0f / NPIX);
}

// ---------------- K5: SE MLP -> sc; wpw_bf16[b,o,c] = inv3[o]*sc[c]*sum_e rw*pw_w ----------------
__global__ void k_se_wpw(const float* __restrict__ s, const float* __restrict__ se_w1,
                         const float* __restrict__ se_b1, const float* __restrict__ se_w2,
                         const float* __restrict__ se_b2, const float* __restrict__ rw,
                         const float* __restrict__ pw_w,
                         const float* __restrict__ bn3_g, const float* __restrict__ bn3_v,
                         unsigned short* __restrict__ wpw) {
    int b = blockIdx.x;
    int tid = threadIdx.x;
    __shared__ float sl[HID];
    __shared__ float zl[RED];
    __shared__ float scl[HID];
    for (int i = tid; i < HID; i += 256) sl[i] = s[(size_t)b * HID + i];
    __syncthreads();
    if (tid < RED) {
        float a = se_b1[tid];
        for (int c = 0; c < HID; ++c) a += sl[c] * se_w1[tid * HID + c];
        zl[tid] = a * sigmoidf_(a);
    }
    __syncthreads();
    for (int c = tid; c < HID; c += 256) {
        float a = se_b2[c];
#pragma unroll
        for (int r = 0; r < RED; ++r) a += zl[r] * se_w2[c * RED + r];
        scl[c] = sigmoidf_(a);
    }
    __syncthreads();
    float rwl[E];
#pragma unroll
    for (int e = 0; e < E; ++e) rwl[e] = rw[b * E + e];
    unsigned short* wb = wpw + (size_t)b * COUT * HID;
    for (int i = tid; i < COUT * HID; i += 256) {
        int o = i / HID, c = i % HID;
        float a = 0.f;
#pragma unroll
        for (int e = 0; e < E; ++e) a += rwl[e] * pw_w[(size_t)e * COUT * HID + i];
        float inv3 = bn3_g[o] * rsqrtf(bn3_v[o] + EPS);
        wb[i] = f2bf(a * inv3 * scl[c]);
    }
}

// ---------------- K6: pointwise GEMM (MFMA bf16) + BN3 shift + residual -> out ----------------
// block = (n-chunk of 112 px, b); 7 waves; wave = one n-frag; all 6 m-frags in acc; K staged 96/stage
__global__ __launch_bounds__(448) void k_pw_mfma(
    const __hip_bfloat16* __restrict__ hid, const unsigned short* __restrict__ wpw,  // [b][96][576] bf16
    const float* __restrict__ x,
    const float* __restrict__ bn3_g, const float* __restrict__ bn3_b,
    const float* __restrict__ bn3_m, const float* __restrict__ bn3_v,
    float* __restrict__ out) {
    int nc = blockIdx.x;  // 0..6
    int b = blockIdx.y;
    int tid = threadIdx.x;
    int lane = tid & 63, nf = tid >> 6;  // wave id = n-frag
    int col = lane & 15, g = lane >> 4;
    __shared__ unsigned short Wl[96 * 104];  // [m=96][k=96 pad 104]
    __shared__ unsigned short Ht[96 * 116];  // [k=96][px=112 pad 116]
    __shared__ float inv3s[COUT], sh3s[COUT];
    if (tid < COUT) {
        float inv = bn3_g[tid] * rsqrtf(bn3_v[tid] + EPS);
        inv3s[tid] = inv;
        sh3s[tid] = bn3_b[tid] - bn3_m[tid] * inv;
    }
    const unsigned short* hb = (const unsigned short*)hid + (size_t)b * HID * NPIX + nc * 112;
    const unsigned short* wb = wpw + (size_t)b * COUT * HID;
    f32x4 acc[6];
#pragma unroll
    for (int m = 0; m < 6; ++m) acc[m] = (f32x4){0.f, 0.f, 0.f, 0.f};

    for (int ks = 0; ks < 6; ++ks) {
        __syncthreads();
        // stage W tile [96 m][96 k] as uint pairs
        for (int i = tid; i < 96 * 48; i += 448) {
            int m = i / 48, k2 = i % 48;
            *(uint*)&Wl[m * 104 + 2 * k2] = *(const uint*)&wb[m * HID + ks * 96 + 2 * k2];
        }
        // stage H tile [96 k][112 px] as uint pairs
        for (int i = tid; i < 96 * 56; i += 448) {
            int k = i / 56, p2 = i % 56;
            *(uint*)&Ht[k * 116 + 2 * p2] = *(const uint*)&hb[((size_t)(ks * 96 + k)) * NPIX + 2 * p2];
        }
        __syncthreads();
#pragma unroll
        for (int kk = 0; kk < 3; ++kk) {
            int k0 = kk * 32 + 8 * g;
            short8v bfr;
#pragma unroll
            for (int j = 0; j < 8; ++j) bfr[j] = (short)Ht[(k0 + j) * 116 + nf * 16 + col];
#pragma unroll
            for (int m = 0; m < 6; ++m) {
                short8v af = *(const short8v*)&Wl[(m * 16 + col) * 104 + kk * 32 + 8 * g];
                acc[m] = __builtin_amdgcn_mfma_f32_16x16x32_bf16(af, bfr, acc[m], 0, 0, 0);
            }
        }
    }
    // epilogue: BN3 shift + residual, fp32 out
    int px = nc * 112 + nf * 16 + col;
#pragma unroll
    for (int m = 0; m < 6; ++m) {
#pragma unroll
        for (int r = 0; r < 4; ++r) {
            int oc = m * 16 + 4 * g + r;
            size_t off = ((size_t)b * COUT + oc) * NPIX + px;
            out[off] = acc[m][r] + sh3s[oc] + x[off];
        }
    }
}

extern "C" void kernel_launch(void* const* d_in, const int* in_sizes, int n_in,
                              void* d_out, int out_size, void* d_ws, size_t ws_size,
                              hipStream_t stream) {
    const float* x     = (const float*)d_in[0];
    const float* r_w1  = (const float*)d_in[1];
    const float* r_b1  = (const float*)d_in[2];
    const float* r_w2  = (const float*)d_in[3];
    const float* r_b2  = (const float*)d_in[4];
    const float* exp_w = (const float*)d_in[5];
    const float* bn1_g = (const float*)d_in[6];
    const float* bn1_b = (const float*)d_in[7];
    const float* bn1_m = (const float*)d_in[8];
    const float* bn1_v = (const float*)d_in[9];
    const float* dw_w  = (const float*)d_in[10];
    const float* bn2_g = (const float*)d_in[11];
    const float* bn2_b = (const float*)d_in[12];
    const float* bn2_m = (const float*)d_in[13];
    const float* bn2_v = (const float*)d_in[14];
    const float* se_w1 = (const float*)d_in[15];
    const float* se_b1 = (const float*)d_in[16];
    const float* se_w2 = (const float*)d_in[17];
    const float* se_b2 = (const float*)d_in[18];
    const float* pw_w  = (const float*)d_in[19];
    const float* bn3_g = (const float*)d_in[20];
    const float* bn3_b = (const float*)d_in[21];
    const float* bn3_m = (const float*)d_in[22];
    const float* bn3_v = (const float*)d_in[23];
    float* out = (float*)d_out;

    char* ws = (char*)d_ws;
    float* rw                 = (float*)(ws + 0);        // 1 KB
    float* kern               = (float*)(ws + 1024);     // 3.69 MB
    float* s                  = (float*)(ws + 3687424);  // 147 KB
    unsigned short* exp_w_bf  = (unsigned short*)(ws + 3834880);   // 110 KB
    unsigned short* wpw_bf    = (unsigned short*)(ws + 3945472);   // 7.08 MB
    __hip_bfloat16* hid       = (__hip_bfloat16*)(ws + 11023360);  // 57.8 MB

    k_routing<<<B, 256, 0, stream>>>(x, r_w1, r_b1, r_w2, r_b2, rw);
    k_kern_agg<<<(B * HID * 25 + 255) / 256, 256, 0, stream>>>(rw, dw_w, bn2_g, bn2_v, kern);
    k_wcvt<<<(HID * CIN + 255) / 256, 256, 0, stream>>>(exp_w, exp_w_bf);
    k_expand_mfma<<<dim3(7, B), 256, 0, stream>>>(x, exp_w_bf, bn1_g, bn1_b, bn1_m, bn1_v, hid);
    k_dw<<<dim3(36, B), 256, 0, stream>>>(hid, kern, bn2_g, bn2_b, bn2_m, bn2_v, s);
    k_se_wpw<<<B, 256, 0, stream>>>(s, se_w1, se_b1, se_w2, se_b2, rw, pw_w, bn3_g, bn3_v, wpw_bf);
    k_pw_mfma<<<dim3(7, B), 448, 0, stream>>>(hid, wpw_bf, x, bn3_g, bn3_b, bn3_m, bn3_v, out);
}

// Round 3
// 335.214 us; speedup vs baseline: 2.1012x; 1.3739x over previous
//
#include <hip/hip_runtime.h>
#include <hip/hip_bf16.h>
#include <math.h>

#define B 64
#define CIN 96
#define HH 28
#define WW 28
#define NPIX 784
#define E 4
#define HID 576
#define RED 24
#define RHID 24
#define COUT 96
#define EPS 1e-3f

typedef __attribute__((ext_vector_type(8))) short short8v;
typedef __attribute__((ext_vector_type(4))) float f32x4;

__device__ __forceinline__ float sigmoidf_(float v) { return 1.0f / (1.0f + __expf(-v)); }

__device__ __forceinline__ unsigned short f2bf(float v) {
    __hip_bfloat16 h = __float2bfloat16(v);
    return *reinterpret_cast<unsigned short*>(&h);
}

// ---------------- K1a: pool[b][c] = mean over pixels; one wave per (b,c) row ----------------
__global__ __launch_bounds__(256) void k_pool(const float* __restrict__ x, float* __restrict__ pool) {
    int row = blockIdx.x * 4 + (threadIdx.x >> 6);  // b*CIN + c  (0..6143)
    int lane = threadIdx.x & 63;
    const float4* xr = reinterpret_cast<const float4*>(x + (size_t)row * NPIX);  // 196 float4
    float s = 0.f;
    for (int i = lane; i < 196; i += 64) {
        float4 v = xr[i];
        s += v.x + v.y + v.z + v.w;
    }
#pragma unroll
    for (int off = 32; off > 0; off >>= 1) s += __shfl_down(s, off);
    if (lane == 0) pool[row] = s * (1.0f / NPIX);
}

// ---------------- K1b: MLP + softmax for all samples; 1 block, thread t = sample t ----------------
__global__ __launch_bounds__(256) void k_mlp(const float* __restrict__ pool,
                                             const float* __restrict__ r_w1, const float* __restrict__ r_b1,
                                             const float* __restrict__ r_w2, const float* __restrict__ r_b2,
                                             float* __restrict__ rw) {
    __shared__ float w1[RHID * CIN];
    __shared__ float b1s[RHID];
    __shared__ float w2[E * RHID];
    __shared__ float b2s[E];
    __shared__ float pl[B * CIN];
    int tid = threadIdx.x;
    for (int i = tid; i < RHID * CIN; i += 256) w1[i] = r_w1[i];
    if (tid < RHID) b1s[tid] = r_b1[tid];
    if (tid < E * RHID) w2[tid] = r_w2[tid];
    if (tid < E) b2s[tid] = r_b2[tid];
    for (int i = tid; i < B * CIN; i += 256) pl[i] = pool[i];
    __syncthreads();
    if (tid < B) {
        const float* p = pl + tid * CIN;
        float hdn[RHID];
#pragma unroll
        for (int r = 0; r < RHID; ++r) {
            float a = b1s[r];
            for (int c = 0; c < CIN; ++c) a += p[c] * w1[r * CIN + c];
            hdn[r] = fmaxf(a, 0.f);
        }
        float lg[E];
        float mx = -1e30f;
#pragma unroll
        for (int e = 0; e < E; ++e) {
            float a = b2s[e];
#pragma unroll
            for (int r = 0; r < RHID; ++r) a += hdn[r] * w2[e * RHID + r];
            lg[e] = a;
            mx = fmaxf(mx, a);
        }
        float den = 0.f;
#pragma unroll
        for (int e = 0; e < E; ++e) { lg[e] = __expf(lg[e] - mx); den += lg[e]; }
#pragma unroll
        for (int e = 0; e < E; ++e) rw[tid * E + e] = lg[e] / den;
    }
}

// ---------------- K2b: exp_w -> bf16 ----------------
__global__ void k_wcvt(const float* __restrict__ w, unsigned short* __restrict__ wb) {
    int i = blockIdx.x * blockDim.x + threadIdx.x;
    if (i < HID * CIN) wb[i] = f2bf(w[i]);
}

// ---------------- K3: expand GEMM (MFMA bf16) + BN1 + SiLU -> hid (bf16 [b][c][p]) ----------------
__global__ __launch_bounds__(256) void k_expand_mfma(
    const float* __restrict__ x, const unsigned short* __restrict__ w_bf,  // [576][96] bf16
    const float* __restrict__ bn1_g, const float* __restrict__ bn1_b,
    const float* __restrict__ bn1_m, const float* __restrict__ bn1_v,
    __hip_bfloat16* __restrict__ hid) {
    int nc = blockIdx.x;  // 0..6
    int b = blockIdx.y;
    int tid = threadIdx.x;
    int lane = tid & 63, wv = tid >> 6;
    int col = lane & 15, g = lane >> 4;
    __shared__ unsigned short xt[96 * 116];  // [k=96][px=112 pad 116] bf16
    __shared__ float inv1s[HID], sh1s[HID];

    for (int i = tid; i < HID; i += 256) {
        float inv = bn1_g[i] * rsqrtf(bn1_v[i] + EPS);
        inv1s[i] = inv;
        sh1s[i] = bn1_b[i] - bn1_m[i] * inv;
    }
    const float* xb = x + (size_t)b * CIN * NPIX + nc * 112;
    for (int i = tid; i < 96 * 112; i += 256) {
        int c = i / 112, p = i % 112;
        xt[c * 116 + p] = f2bf(xb[c * NPIX + p]);
    }
    __syncthreads();

    const short8v* wv8 = reinterpret_cast<const short8v*>(w_bf);
    for (int nf = 0; nf < 7; ++nf) {
        int pcol = nf * 16 + col;
        short8v bfr[3];
#pragma unroll
        for (int kk = 0; kk < 3; ++kk) {
            int k0 = kk * 32 + 8 * g;
#pragma unroll
            for (int j = 0; j < 8; ++j) bfr[kk][j] = (short)xt[(k0 + j) * 116 + pcol];
        }
        int px = nc * 112 + pcol;
#pragma unroll
        for (int mi = 0; mi < 9; ++mi) {
            int mb = (wv * 9 + mi) * 16;
            f32x4 acc = {0.f, 0.f, 0.f, 0.f};
#pragma unroll
            for (int kk = 0; kk < 3; ++kk) {
                short8v af = wv8[((mb + col) * 96 + kk * 32 + 8 * g) >> 3];
                acc = __builtin_amdgcn_mfma_f32_16x16x32_bf16(af, bfr[kk], acc, 0, 0, 0);
            }
#pragma unroll
            for (int r = 0; r < 4; ++r) {
                int oc = mb + 4 * g + r;
                float t = acc[r] * inv1s[oc] + sh1s[oc];
                float u = t * sigmoidf_(t);
                hid[((size_t)b * HID + oc) * NPIX + px] = __float2bfloat16(u);
            }
        }
    }
}

// ---------------- K4: depthwise 5x5 (expert-agg folded in) + BN2 + SiLU + channel means ----------------
__global__ __launch_bounds__(256, 2) void k_dw(
    __hip_bfloat16* __restrict__ hid, const float* __restrict__ rw,
    const float* __restrict__ dw_w,
    const float* __restrict__ bn2_g, const float* __restrict__ bn2_b,
    const float* __restrict__ bn2_m, const float* __restrict__ bn2_v,
    float* __restrict__ s_out) {
    const int CT = 16;
    int ct = blockIdx.x;  // 0..35
    int b = blockIdx.y;
    int tid = threadIdx.x;
    int cb = ct * CT;
    __shared__ float plane[CT][NPIX];  // 50 KB
    __shared__ float kl[CT][25];
    __shared__ float ssum[CT];
    __hip_bfloat16* hb = hid + ((size_t)b * HID + cb) * NPIX;
    for (int i = tid; i < CT * NPIX; i += 256) plane[i / NPIX][i % NPIX] = __bfloat162float(hb[i]);
    {
        float rwl[E];
#pragma unroll
        for (int e = 0; e < E; ++e) rwl[e] = rw[b * E + e];
        for (int i = tid; i < CT * 25; i += 256) {
            int ci = i / 25, j = i % 25;
            int c = cb + ci;
            float a = 0.f;
#pragma unroll
            for (int e = 0; e < E; ++e) a += rwl[e] * dw_w[((size_t)e * HID + c) * 25 + j];
            float inv2 = bn2_g[c] * rsqrtf(bn2_v[c] + EPS);
            kl[ci][j] = a * inv2;
        }
    }
    if (tid < CT) ssum[tid] = 0.f;
    __syncthreads();
    for (int pass = 0; pass < 2; ++pass) {
        int col = pass * 256 + tid;
        if (col < CT * WW) {
            int ci = col / WW, w = col % WW;
            float k[25];
#pragma unroll
            for (int j = 0; j < 25; ++j) k[j] = kl[ci][j];
            float win[5][5];
#pragma unroll
            for (int i = 0; i < 5; ++i) {
                int hr = i - 2;
#pragma unroll
                for (int j = 0; j < 5; ++j) {
                    int wc = w - 2 + j;
                    win[i][j] = (hr >= 0 && hr < HH && wc >= 0 && wc < WW) ? plane[ci][hr * WW + wc] : 0.f;
                }
            }
            int c = cb + ci;
            float inv2 = bn2_g[c] * rsqrtf(bn2_v[c] + EPS);
            float sh2 = bn2_b[c] - bn2_m[c] * inv2;
            float csum = 0.f;
#pragma unroll
            for (int h = 0; h < HH; ++h) {
                float o = 0.f;
#pragma unroll
                for (int i = 0; i < 5; ++i)
#pragma unroll
                    for (int j = 0; j < 5; ++j) o += win[i][j] * k[i * 5 + j];
                float t = o + sh2;
                float u = t * sigmoidf_(t);
                csum += u;
                hb[ci * NPIX + h * WW + w] = __float2bfloat16(u);
#pragma unroll
                for (int i = 0; i < 4; ++i)
#pragma unroll
                    for (int j = 0; j < 5; ++j) win[i][j] = win[i + 1][j];
                int hn = h + 3;
#pragma unroll
                for (int j = 0; j < 5; ++j) {
                    int wc = w - 2 + j;
                    win[4][j] = (hn < HH && wc >= 0 && wc < WW) ? plane[ci][hn * WW + wc] : 0.f;
                }
            }
            atomicAdd(&ssum[ci], csum);
        }
    }
    __syncthreads();
    if (tid < CT) s_out[(size_t)b * HID + cb + tid] = ssum[tid] * (1.0f / NPIX);
}

// ---------------- K5: SE MLP (recomputed per block) + wpw slice; grid (6, B) ----------------
__global__ __launch_bounds__(256) void k_se_wpw(
    const float* __restrict__ s, const float* __restrict__ se_w1,
    const float* __restrict__ se_b1, const float* __restrict__ se_w2,
    const float* __restrict__ se_b2, const float* __restrict__ rw,
    const float* __restrict__ pw_w,
    const float* __restrict__ bn3_g, const float* __restrict__ bn3_v,
    unsigned short* __restrict__ wpw) {
    int seg = blockIdx.x;  // 0..5 -> oc range
    int b = blockIdx.y;
    int tid = threadIdx.x;
    __shared__ float sl[HID];
    __shared__ float zl[RED];
    __shared__ float scl[HID];
    for (int i = tid; i < HID; i += 256) sl[i] = s[(size_t)b * HID + i];
    __syncthreads();
    if (tid < RED) {
        float a = se_b1[tid];
        for (int c = 0; c < HID; ++c) a += sl[c] * se_w1[tid * HID + c];
        zl[tid] = a * sigmoidf_(a);
    }
    __syncthreads();
    for (int c = tid; c < HID; c += 256) {
        float a = se_b2[c];
#pragma unroll
        for (int r = 0; r < RED; ++r) a += zl[r] * se_w2[c * RED + r];
        scl[c] = sigmoidf_(a);
    }
    __syncthreads();
    float rwl[E];
#pragma unroll
    for (int e = 0; e < E; ++e) rwl[e] = rw[b * E + e];
    unsigned short* wb = wpw + (size_t)b * COUT * HID;
    for (int i = tid; i < 16 * HID; i += 256) {
        int o = seg * 16 + i / HID, c = i % HID;
        float a = 0.f;
#pragma unroll
        for (int e = 0; e < E; ++e) a += rwl[e] * pw_w[((size_t)e * COUT + o) * HID + c];
        float inv3 = bn3_g[o] * rsqrtf(bn3_v[o] + EPS);
        wb[o * HID + c] = f2bf(a * inv3 * scl[c]);
    }
}

// ---------------- K6: pointwise GEMM (MFMA bf16) + BN3 shift + residual -> out ----------------
__global__ __launch_bounds__(448) void k_pw_mfma(
    const __hip_bfloat16* __restrict__ hid, const unsigned short* __restrict__ wpw,  // [b][96][576] bf16
    const float* __restrict__ x,
    const float* __restrict__ bn3_g, const float* __restrict__ bn3_b,
    const float* __restrict__ bn3_m, const float* __restrict__ bn3_v,
    float* __restrict__ out) {
    int nc = blockIdx.x;  // 0..6
    int b = blockIdx.y;
    int tid = threadIdx.x;
    int lane = tid & 63, nf = tid >> 6;
    int col = lane & 15, g = lane >> 4;
    __shared__ unsigned short Wl[96 * 104];  // [m=96][k=96 pad 104]
    __shared__ unsigned short Ht[96 * 116];  // [k=96][px=112 pad 116]
    __shared__ float inv3s[COUT], sh3s[COUT];
    if (tid < COUT) {
        float inv = bn3_g[tid] * rsqrtf(bn3_v[tid] + EPS);
        inv3s[tid] = inv;
        sh3s[tid] = bn3_b[tid] - bn3_m[tid] * inv;
    }
    const unsigned short* hb = (const unsigned short*)hid + (size_t)b * HID * NPIX + nc * 112;
    const unsigned short* wb = wpw + (size_t)b * COUT * HID;
    f32x4 acc[6];
#pragma unroll
    for (int m = 0; m < 6; ++m) acc[m] = (f32x4){0.f, 0.f, 0.f, 0.f};

    for (int ks = 0; ks < 6; ++ks) {
        __syncthreads();
        for (int i = tid; i < 96 * 48; i += 448) {
            int m = i / 48, k2 = i % 48;
            *(uint*)&Wl[m * 104 + 2 * k2] = *(const uint*)&wb[m * HID + ks * 96 + 2 * k2];
        }
        for (int i = tid; i < 96 * 56; i += 448) {
            int k = i / 56, p2 = i % 56;
            *(uint*)&Ht[k * 116 + 2 * p2] = *(const uint*)&hb[((size_t)(ks * 96 + k)) * NPIX + 2 * p2];
        }
        __syncthreads();
#pragma unroll
        for (int kk = 0; kk < 3; ++kk) {
            int k0 = kk * 32 + 8 * g;
            short8v bfr;
#pragma unroll
            for (int j = 0; j < 8; ++j) bfr[j] = (short)Ht[(k0 + j) * 116 + nf * 16 + col];
#pragma unroll
            for (int m = 0; m < 6; ++m) {
                short8v af = *(const short8v*)&Wl[(m * 16 + col) * 104 + kk * 32 + 8 * g];
                acc[m] = __builtin_amdgcn_mfma_f32_16x16x32_bf16(af, bfr, acc[m], 0, 0, 0);
            }
        }
    }
    int px = nc * 112 + nf * 16 + col;
#pragma unroll
    for (int m = 0; m < 6; ++m) {
#pragma unroll
        for (int r = 0; r < 4; ++r) {
            int oc = m * 16 + 4 * g + r;
            size_t off = ((size_t)b * COUT + oc) * NPIX + px;
            out[off] = acc[m][r] + sh3s[oc] + x[off];
        }
    }
}

extern "C" void kernel_launch(void* const* d_in, const int* in_sizes, int n_in,
                              void* d_out, int out_size, void* d_ws, size_t ws_size,
                              hipStream_t stream) {
    const float* x     = (const float*)d_in[0];
    const float* r_w1  = (const float*)d_in[1];
    const float* r_b1  = (const float*)d_in[2];
    const float* r_w2  = (const float*)d_in[3];
    const float* r_b2  = (const float*)d_in[4];
    const float* exp_w = (const float*)d_in[5];
    const float* bn1_g = (const float*)d_in[6];
    const float* bn1_b = (const float*)d_in[7];
    const float* bn1_m = (const float*)d_in[8];
    const float* bn1_v = (const float*)d_in[9];
    const float* dw_w  = (const float*)d_in[10];
    const float* bn2_g = (const float*)d_in[11];
    const float* bn2_b = (const float*)d_in[12];
    const float* bn2_m = (const float*)d_in[13];
    const float* bn2_v = (const float*)d_in[14];
    const float* se_w1 = (const float*)d_in[15];
    const float* se_b1 = (const float*)d_in[16];
    const float* se_w2 = (const float*)d_in[17];
    const float* se_b2 = (const float*)d_in[18];
    const float* pw_w  = (const float*)d_in[19];
    const float* bn3_g = (const float*)d_in[20];
    const float* bn3_b = (const float*)d_in[21];
    const float* bn3_m = (const float*)d_in[22];
    const float* bn3_v = (const float*)d_in[23];
    float* out = (float*)d_out;

    char* ws = (char*)d_ws;
    float* rw                 = (float*)(ws + 0);        // 1 KB
    float* pool               = (float*)(ws + 1024);     // 24 KB
    float* s                  = (float*)(ws + 26624);    // 147 KB
    unsigned short* exp_w_bf  = (unsigned short*)(ws + 174336);   // 110 KB
    unsigned short* wpw_bf    = (unsigned short*)(ws + 285184);   // 7.08 MB
    __hip_bfloat16* hid       = (__hip_bfloat16*)(ws + 7363328);  // 57.8 MB

    k_pool<<<B * CIN / 4, 256, 0, stream>>>(x, pool);
    k_mlp<<<1, 256, 0, stream>>>(pool, r_w1, r_b1, r_w2, r_b2, rw);
    k_wcvt<<<(HID * CIN + 255) / 256, 256, 0, stream>>>(exp_w, exp_w_bf);
    k_expand_mfma<<<dim3(7, B), 256, 0, stream>>>(x, exp_w_bf, bn1_g, bn1_b, bn1_m, bn1_v, hid);
    k_dw<<<dim3(36, B), 256, 0, stream>>>(hid, rw, dw_w, bn2_g, bn2_b, bn2_m, bn2_v, s);
    k_se_wpw<<<dim3(6, B), 256, 0, stream>>>(s, se_w1, se_b1, se_w2, se_b2, rw, pw_w, bn3_g, bn3_v, wpw_bf);
    k_pw_mfma<<<dim3(7, B), 448, 0, stream>>>(hid, wpw_bf, x, bn3_g, bn3_b, bn3_m, bn3_v, out);
}